// Round 6
// baseline (5338.787 us; speedup 1.0000x reference)
//
#include <hip/hip_runtime.h>
#include <hip/hip_bf16.h>

#define N_NODES 40000
#define N_EDGES 640000
#define DIM_IN 64
#define DIM_H 128
#define DIM_OUT 32
#define DIM_ED 16
#define HEADS 2
#define NEG_SLOPE 0.2f
#define NEG_INF (-__builtin_inff())

// ---------------------------------------------------------------------------
// degree count (1 int atomic per edge)
// ---------------------------------------------------------------------------
__global__ void deg_kernel(const int* __restrict__ tgt, int* __restrict__ deg, int E_) {
    int e = blockIdx.x * 256 + threadIdx.x;
    if (e >= E_) return;
    atomicAdd(&deg[tgt[e]], 1);
}

// ---------------------------------------------------------------------------
// exclusive scan of (deg[i]+1) -> off[0..n]; wave-shuffle scan
// ---------------------------------------------------------------------------
__global__ __launch_bounds__(1024) void scan_kernel(const int* __restrict__ deg,
                                                    int* __restrict__ off, int n) {
    __shared__ int wsum[16];
    __shared__ int carry_s;
    int tid = threadIdx.x;
    int wv = tid >> 6, ln = tid & 63;
    if (tid == 0) carry_s = 0;
    __syncthreads();
    for (int base = 0; base < n; base += 1024) {
        int i = base + tid;
        int v = (i < n) ? (deg[i] + 1) : 0;  // +1 = self loop
        int s = v;
        #pragma unroll
        for (int d = 1; d < 64; d <<= 1) {
            int u = __shfl_up(s, d, 64);
            if (ln >= d) s += u;
        }
        if (ln == 63) wsum[wv] = s;
        __syncthreads();
        int woff = 0;
        #pragma unroll
        for (int w = 0; w < 16; w++) woff += (w < wv) ? wsum[w] : 0;
        int carry = carry_s;
        if (i < n) off[i] = carry + woff + s - v;  // exclusive
        __syncthreads();
        if (tid == 1023) carry_s = carry + woff + s;
        __syncthreads();
    }
    if (tid == 0) off[n] = carry_s;
}

// scatter edge id AND source node id (kills one pointer-chase level in attn)
__global__ void scatter_kernel(const int* __restrict__ tgt, const int* __restrict__ src,
                               const int* __restrict__ off, int* __restrict__ cursor,
                               int* __restrict__ eid, int* __restrict__ csrc, int E_, int n) {
    int e = blockIdx.x * 256 + threadIdx.x;
    if (e >= E_ + n) return;
    int t, s;
    if (e < E_) { t = tgt[e]; s = src[e]; }
    else        { t = e - E_; s = e - E_; }
    int pos = atomicAdd(&cursor[t], 1);
    int slot = off[t] + pos;
    eid[slot] = e;
    csrc[slot] = s;
}

// ---------------------------------------------------------------------------
// ea_mean from CSR: 16 lanes per node, one channel each; no atomics
// ---------------------------------------------------------------------------
__global__ __launch_bounds__(256) void ea_mean_kernel(
    const float* __restrict__ edge_attr, const int* __restrict__ csr_eid,
    const int* __restrict__ csr_off, float* __restrict__ ea_mean, int n, int E_) {
    int tid = blockIdx.x * 256 + threadIdx.x;
    int node = tid >> 4;
    int c = tid & 15;
    if (node >= n) return;
    int beg = csr_off[node], end = csr_off[node + 1];
    float s = 0.f;
    int cnt = 0;
    for (int ii = beg; ii < end; ii++) {
        int eid = csr_eid[ii];
        if (eid < E_) { s += edge_attr[(size_t)eid * DIM_ED + c]; cnt++; }
    }
    ea_mean[(size_t)node * DIM_ED + c] = s / fmaxf((float)cnt, 1.0f);
}

// ---------------------------------------------------------------------------
// in_proj: h = relu(x @ W0 + b0)
// ---------------------------------------------------------------------------
__global__ __launch_bounds__(128) void in_proj_kernel(
    const float* __restrict__ x, const float* __restrict__ W0, const float* __restrict__ b0,
    float* __restrict__ h) {
    int nb = blockIdx.x * 8;
    __shared__ float xs[8][DIM_IN];
    int tid = threadIdx.x;  // 128
    for (int i = tid; i < 8 * DIM_IN; i += 128) xs[i >> 6][i & 63] = x[(size_t)nb * DIM_IN + i];
    __syncthreads();
    float acc[8];
    float bias = b0[tid];
    #pragma unroll
    for (int j = 0; j < 8; j++) acc[j] = bias;
    for (int k = 0; k < DIM_IN; k++) {
        float w = W0[k * DIM_H + tid];
        #pragma unroll
        for (int j = 0; j < 8; j++) acc[j] += xs[j][k] * w;
    }
    #pragma unroll
    for (int j = 0; j < 8; j++) h[(size_t)(nb + j) * DIM_H + tid] = fmaxf(acc[j], 0.0f);
}

// ---------------------------------------------------------------------------
// node projections: xl = h@Wl+bl, xr = h@Wr+br
// ---------------------------------------------------------------------------
__global__ __launch_bounds__(256) void node_proj_kernel(
    const float* __restrict__ h, const float* __restrict__ Wl, const float* __restrict__ bl,
    const float* __restrict__ Wr, const float* __restrict__ br,
    float* __restrict__ xl, float* __restrict__ xr) {
    int nb = blockIdx.x * 8;
    __shared__ float hs[8][DIM_H];
    int tid = threadIdx.x;  // 256
    for (int i = tid; i < 8 * DIM_H; i += 256) hs[i >> 7][i & 127] = h[(size_t)nb * DIM_H + i];
    __syncthreads();
    float accL[8], accR[8];
    float bL = bl[tid], bR = br[tid];
    #pragma unroll
    for (int j = 0; j < 8; j++) { accL[j] = bL; accR[j] = bR; }
    for (int k = 0; k < DIM_H; k++) {
        float wl = Wl[k * 256 + tid];
        float wr = Wr[k * 256 + tid];
        #pragma unroll
        for (int j = 0; j < 8; j++) {
            accL[j] += hs[j][k] * wl;
            accR[j] += hs[j][k] * wr;
        }
    }
    #pragma unroll
    for (int j = 0; j < 8; j++) {
        xl[(size_t)(nb + j) * 256 + tid] = accL[j];
        xr[(size_t)(nb + j) * 256 + tid] = accR[j];
    }
}

// ---------------------------------------------------------------------------
// Fused GATv2 attention + aggregation.
// 2 waves per target node, 2 independent online-softmax states per wave
// (4 independent chains over the edge list -> hides gather + softmax latency).
// Lane owns 4 channels of 256 (=2 heads x 128). Exact softmax merging.
// ---------------------------------------------------------------------------
__global__ __launch_bounds__(256, 4) void gat_attn_kernel(
    const float* __restrict__ xl, const float* __restrict__ xr,
    const float* __restrict__ edge_attr, const float* __restrict__ ea_mean,
    const int* __restrict__ csr_src, const int* __restrict__ csr_eid,
    const int* __restrict__ csr_off,
    const float* __restrict__ We, const float* __restrict__ att, const float* __restrict__ bconv,
    float* __restrict__ h_new, int n, int E_) {
    int tid = threadIdx.x;
    int wave = tid >> 6, lane = tid & 63;
    int w2 = wave >> 1, sub = wave & 1;
    int t = blockIdx.x * 2 + w2;  // grid = n/2 exactly (n even), no guard needed
    int c0 = lane * 4;

    float4 Wcol[DIM_ED];
    #pragma unroll
    for (int k = 0; k < DIM_ED; k++) Wcol[k] = *(const float4*)(We + k * 256 + c0);
    float4 attv = *(const float4*)(att + c0);
    float4 xrt = *(const float4*)(xr + (size_t)t * 256 + c0);

    float4 accA = {0.f, 0.f, 0.f, 0.f}, accB = {0.f, 0.f, 0.f, 0.f};
    float dA = 0.f, dB = 0.f;
    float mA = NEG_INF, mB = NEG_INF;

    int beg = csr_off[t], end = csr_off[t + 1];

    for (int ii = beg + sub; ii < end; ii += 4) {
        int jj = ii + 2;
        bool hasB = (jj < end);       // wave-uniform
        int jc = hasB ? jj : ii;
        // issue all loads for both edges up front
        int sA = csr_src[ii];
        int sB = csr_src[jc];
        int eA = csr_eid[ii];
        int eB = csr_eid[jc];
        const float* eaA = (eA < E_) ? edge_attr + (size_t)eA * DIM_ED
                                     : ea_mean + (size_t)t * DIM_ED;
        const float* eaB = (eB < E_) ? edge_attr + (size_t)eB * DIM_ED
                                     : ea_mean + (size_t)t * DIM_ED;
        float4 xjA = *(const float4*)(xl + (size_t)sA * 256 + c0);
        float4 xjB = *(const float4*)(xl + (size_t)sB * 256 + c0);

        // edge projections, chunked to limit live registers
        float4 efA = {0.f, 0.f, 0.f, 0.f}, efB = {0.f, 0.f, 0.f, 0.f};
        #pragma unroll
        for (int q = 0; q < 4; q++) {
            float4 a4 = *(const float4*)(eaA + q * 4);
            float4 b4 = *(const float4*)(eaB + q * 4);
            float av[4] = {a4.x, a4.y, a4.z, a4.w};
            float bv[4] = {b4.x, b4.y, b4.z, b4.w};
            #pragma unroll
            for (int r = 0; r < 4; r++) {
                float4 w = Wcol[q * 4 + r];
                efA.x += av[r] * w.x; efA.y += av[r] * w.y;
                efA.z += av[r] * w.z; efA.w += av[r] * w.w;
                efB.x += bv[r] * w.x; efB.y += bv[r] * w.y;
                efB.z += bv[r] * w.z; efB.w += bv[r] * w.w;
            }
        }

        float a0 = xjA.x + xrt.x + efA.x; a0 = (a0 > 0.f) ? a0 : NEG_SLOPE * a0;
        float a1 = xjA.y + xrt.y + efA.y; a1 = (a1 > 0.f) ? a1 : NEG_SLOPE * a1;
        float a2 = xjA.z + xrt.z + efA.z; a2 = (a2 > 0.f) ? a2 : NEG_SLOPE * a2;
        float a3 = xjA.w + xrt.w + efA.w; a3 = (a3 > 0.f) ? a3 : NEG_SLOPE * a3;
        float lA = attv.x * a0 + attv.y * a1 + attv.z * a2 + attv.w * a3;
        float b0_ = xjB.x + xrt.x + efB.x; b0_ = (b0_ > 0.f) ? b0_ : NEG_SLOPE * b0_;
        float b1_ = xjB.y + xrt.y + efB.y; b1_ = (b1_ > 0.f) ? b1_ : NEG_SLOPE * b1_;
        float b2_ = xjB.z + xrt.z + efB.z; b2_ = (b2_ > 0.f) ? b2_ : NEG_SLOPE * b2_;
        float b3_ = xjB.w + xrt.w + efB.w; b3_ = (b3_ > 0.f) ? b3_ : NEG_SLOPE * b3_;
        float lB = attv.x * b0_ + attv.y * b1_ + attv.z * b2_ + attv.w * b3_;

        // interleaved 32-lane reductions (two independent chains)
        #pragma unroll
        for (int d = 1; d < 32; d <<= 1) {
            lA += __shfl_xor(lA, d, 64);
            lB += __shfl_xor(lB, d, 64);
        }

        // online softmax update, state A (single exp)
        {
            float mnew = fmaxf(mA, lA);
            float e = __expf(fminf(mA - lA, lA - mA));  // exp(-|diff|); -inf-safe
            bool nm = lA > mA;
            float scale = nm ? e : 1.f;
            float p = nm ? 1.f : e;
            dA = dA * scale + p;
            accA.x = accA.x * scale + p * xjA.x;
            accA.y = accA.y * scale + p * xjA.y;
            accA.z = accA.z * scale + p * xjA.z;
            accA.w = accA.w * scale + p * xjA.w;
            mA = mnew;
        }
        if (hasB) {
            float mnew = fmaxf(mB, lB);
            float e = __expf(fminf(mB - lB, lB - mB));
            bool nm = lB > mB;
            float scale = nm ? e : 1.f;
            float p = nm ? 1.f : e;
            dB = dB * scale + p;
            accB.x = accB.x * scale + p * xjB.x;
            accB.y = accB.y * scale + p * xjB.y;
            accB.z = accB.z * scale + p * xjB.z;
            accB.w = accB.w * scale + p * xjB.w;
            mB = mnew;
        }
    }

    // merge state B into A (exact)
    {
        float mW = fmaxf(mA, mB);
        float e1 = (mA > NEG_INF) ? __expf(mA - mW) : 0.f;
        float e2 = (mB > NEG_INF) ? __expf(mB - mW) : 0.f;
        dA = dA * e1 + dB * e2;
        accA.x = accA.x * e1 + accB.x * e2;
        accA.y = accA.y * e1 + accB.y * e2;
        accA.z = accA.z * e1 + accB.z * e2;
        accA.w = accA.w * e1 + accB.w * e2;
        mA = mW;
    }

    // cross-wave merge via LDS (sub 1 -> sub 0)
    __shared__ float red[2][64][8];
    if (sub == 1) {
        red[w2][lane][0] = accA.x;
        red[w2][lane][1] = accA.y;
        red[w2][lane][2] = accA.z;
        red[w2][lane][3] = accA.w;
        red[w2][lane][4] = mA;
        red[w2][lane][5] = dA;
    }
    __syncthreads();
    if (sub == 0) {
        float m2 = red[w2][lane][4];
        float d2 = red[w2][lane][5];
        float mF = fmaxf(mA, m2);           // mA finite (wave 0 owns slot beg)
        float e1 = __expf(mA - mF);
        float e2 = (m2 > NEG_INF) ? __expf(m2 - mF) : 0.f;
        float dF = dA * e1 + d2 * e2;
        float fx = accA.x * e1 + red[w2][lane][0] * e2;
        float fy = accA.y * e1 + red[w2][lane][1] * e2;
        float fz = accA.z * e1 + red[w2][lane][2] * e2;
        float fw = accA.w * e1 + red[w2][lane][3] * e2;
        float inv = 1.0f / dF;
        float o0 = fx * inv, o1 = fy * inv, o2 = fz * inv, o3 = fw * inv;
        // head mean: pair with lane^32 (same channel, other head)
        float u0 = 0.5f * (o0 + __shfl_xor(o0, 32, 64));
        float u1 = 0.5f * (o1 + __shfl_xor(o1, 32, 64));
        float u2 = 0.5f * (o2 + __shfl_xor(o2, 32, 64));
        float u3 = 0.5f * (o3 + __shfl_xor(o3, 32, 64));
        if (lane < 32) {
            float4 bc = *(const float4*)(bconv + c0);
            float4 ov;
            ov.x = fmaxf(u0 + bc.x, 0.f);
            ov.y = fmaxf(u1 + bc.y, 0.f);
            ov.z = fmaxf(u2 + bc.z, 0.f);
            ov.w = fmaxf(u3 + bc.w, 0.f);
            *(float4*)(h_new + (size_t)t * DIM_H + c0) = ov;
        }
    }
}

// ---------------------------------------------------------------------------
// decoder: out = sigmoid(relu(h@W1+b1)@W2+b2)
// ---------------------------------------------------------------------------
__global__ __launch_bounds__(128) void decoder_kernel(
    const float* __restrict__ h, const float* __restrict__ W1, const float* __restrict__ b1,
    const float* __restrict__ W2, const float* __restrict__ b2, float* __restrict__ out) {
    int nb = blockIdx.x * 4;
    __shared__ float hs[4][DIM_H];
    __shared__ float hid[4][DIM_H];
    int tid = threadIdx.x;  // 128
    for (int i = tid; i < 4 * DIM_H; i += 128) hs[i >> 7][i & 127] = h[(size_t)nb * DIM_H + i];
    __syncthreads();
    float acc[4];
    float bias = b1[tid];
    #pragma unroll
    for (int j = 0; j < 4; j++) acc[j] = bias;
    for (int k = 0; k < DIM_H; k++) {
        float w = W1[k * DIM_H + tid];
        #pragma unroll
        for (int j = 0; j < 4; j++) acc[j] += hs[j][k] * w;
    }
    #pragma unroll
    for (int j = 0; j < 4; j++) hid[j][tid] = fmaxf(acc[j], 0.0f);
    __syncthreads();
    int node = tid >> 5, oc = tid & 31;
    float a = b2[oc];
    for (int k = 0; k < DIM_H; k++) a += hid[node][k] * W2[k * DIM_OUT + oc];
    out[(size_t)(nb + node) * DIM_OUT + oc] = 1.0f / (1.0f + __expf(-a));
}

// ---------------------------------------------------------------------------
extern "C" void kernel_launch(void* const* d_in, const int* in_sizes, int n_in,
                              void* d_out, int out_size, void* d_ws, size_t ws_size,
                              hipStream_t stream) {
    const float* x         = (const float*)d_in[0];
    const int*   edge_index= (const int*)  d_in[1];
    const float* edge_attr = (const float*)d_in[2];
    const float* W0        = (const float*)d_in[3];
    const float* b0        = (const float*)d_in[4];
    const float* Wl        = (const float*)d_in[5];
    const float* bl        = (const float*)d_in[6];
    const float* Wr        = (const float*)d_in[7];
    const float* br        = (const float*)d_in[8];
    const float* We        = (const float*)d_in[9];
    const float* att       = (const float*)d_in[10];
    const float* bconv     = (const float*)d_in[11];
    const float* W1        = (const float*)d_in[12];
    const float* b1        = (const float*)d_in[13];
    const float* W2        = (const float*)d_in[14];
    const float* b2        = (const float*)d_in[15];
    float* out = (float*)d_out;

    const int N_ = N_NODES, E_ = N_EDGES;
    const int* src = edge_index;       // edge_index[0]
    const int* tgt = edge_index + E_;  // edge_index[1]

    char* ws = (char*)d_ws;
    size_t o = 0;
    auto alloc = [&](size_t bytes) -> void* {
        void* p = ws + o;
        o += (bytes + 255) & ~(size_t)255;
        return p;
    };
    float* h0      = (float*)alloc((size_t)N_ * DIM_H * 4);
    float* h1      = (float*)alloc((size_t)N_ * DIM_H * 4);
    float* xl      = (float*)alloc((size_t)N_ * 256 * 4);
    float* xr      = (float*)alloc((size_t)N_ * 256 * 4);
    float* ea_mean = (float*)alloc((size_t)N_ * DIM_ED * 4);
    int*   deg     = (int*)alloc((size_t)N_ * 4);
    int*   off     = (int*)alloc((size_t)(N_ + 1) * 4);
    int*   cursor  = (int*)alloc((size_t)N_ * 4);
    int*   eid     = (int*)alloc((size_t)(E_ + N_) * 4);
    int*   csrc    = (int*)alloc((size_t)(E_ + N_) * 4);

    hipMemsetAsync(deg, 0, (size_t)N_ * 4, stream);
    hipMemsetAsync(cursor, 0, (size_t)N_ * 4, stream);

    deg_kernel<<<(E_ + 255) / 256, 256, 0, stream>>>(tgt, deg, E_);
    scan_kernel<<<1, 1024, 0, stream>>>(deg, off, N_);
    scatter_kernel<<<(E_ + N_ + 255) / 256, 256, 0, stream>>>(tgt, src, off, cursor, eid, csrc, E_, N_);
    ea_mean_kernel<<<(N_ * DIM_ED + 255) / 256, 256, 0, stream>>>(edge_attr, eid, off, ea_mean, N_, E_);

    in_proj_kernel<<<N_ / 8, 128, 0, stream>>>(x, W0, b0, h0);

    float* hc = h0;
    float* hn = h1;
    for (int l = 0; l < 3; l++) {
        node_proj_kernel<<<N_ / 8, 256, 0, stream>>>(
            hc, Wl + (size_t)l * DIM_H * 256, bl + (size_t)l * 256,
            Wr + (size_t)l * DIM_H * 256, br + (size_t)l * 256, xl, xr);
        gat_attn_kernel<<<N_ / 2, 256, 0, stream>>>(
            xl, xr, edge_attr, ea_mean, csrc, eid, off,
            We + (size_t)l * DIM_ED * 256, att + (size_t)l * 256, bconv + (size_t)l * DIM_H,
            hn, N_, E_);
        float* tswap = hc; hc = hn; hn = tswap;
    }
    decoder_kernel<<<N_ / 4, 128, 0, stream>>>(hc, W1, b1, W2, b2, out);
}

// Round 7
// 2892.955 us; speedup vs baseline: 1.8454x; 1.8454x over previous
//
#include <hip/hip_runtime.h>
#include <hip/hip_bf16.h>

#define N_NODES 40000
#define N_EDGES 640000
#define DIM_IN 64
#define DIM_H 128
#define DIM_OUT 32
#define DIM_ED 16
#define HEADS 2
#define NEG_SLOPE 0.2f
#define NEG_INF (-__builtin_inff())

// ---------------------------------------------------------------------------
// degree count (1 int atomic per edge)
// ---------------------------------------------------------------------------
__global__ void deg_kernel(const int* __restrict__ tgt, int* __restrict__ deg, int E_) {
    int e = blockIdx.x * 256 + threadIdx.x;
    if (e >= E_) return;
    atomicAdd(&deg[tgt[e]], 1);
}

// ---------------------------------------------------------------------------
// exclusive scan of (deg[i]+1) -> off[0..n]; wave-shuffle scan
// ---------------------------------------------------------------------------
__global__ __launch_bounds__(1024) void scan_kernel(const int* __restrict__ deg,
                                                    int* __restrict__ off, int n) {
    __shared__ int wsum[16];
    __shared__ int carry_s;
    int tid = threadIdx.x;
    int wv = tid >> 6, ln = tid & 63;
    if (tid == 0) carry_s = 0;
    __syncthreads();
    for (int base = 0; base < n; base += 1024) {
        int i = base + tid;
        int v = (i < n) ? (deg[i] + 1) : 0;  // +1 = self loop
        int s = v;
        #pragma unroll
        for (int d = 1; d < 64; d <<= 1) {
            int u = __shfl_up(s, d, 64);
            if (ln >= d) s += u;
        }
        if (ln == 63) wsum[wv] = s;
        __syncthreads();
        int woff = 0;
        #pragma unroll
        for (int w = 0; w < 16; w++) woff += (w < wv) ? wsum[w] : 0;
        int carry = carry_s;
        if (i < n) off[i] = carry + woff + s - v;  // exclusive
        __syncthreads();
        if (tid == 1023) carry_s = carry + woff + s;
        __syncthreads();
    }
    if (tid == 0) off[n] = carry_s;
}

// scatter edge id AND source node id (kills one pointer-chase level in attn)
__global__ void scatter_kernel(const int* __restrict__ tgt, const int* __restrict__ src,
                               const int* __restrict__ off, int* __restrict__ cursor,
                               int* __restrict__ eid, int* __restrict__ csrc, int E_, int n) {
    int e = blockIdx.x * 256 + threadIdx.x;
    if (e >= E_ + n) return;
    int t, s;
    if (e < E_) { t = tgt[e]; s = src[e]; }
    else        { t = e - E_; s = e - E_; }
    int pos = atomicAdd(&cursor[t], 1);
    int slot = off[t] + pos;
    eid[slot] = e;
    csrc[slot] = s;
}

// ---------------------------------------------------------------------------
// ea_mean from CSR: 16 lanes per node, one channel each; no atomics
// ---------------------------------------------------------------------------
__global__ __launch_bounds__(256) void ea_mean_kernel(
    const float* __restrict__ edge_attr, const int* __restrict__ csr_eid,
    const int* __restrict__ csr_off, float* __restrict__ ea_mean, int n, int E_) {
    int tid = blockIdx.x * 256 + threadIdx.x;
    int node = tid >> 4;
    int c = tid & 15;
    if (node >= n) return;
    int beg = csr_off[node], end = csr_off[node + 1];
    float s = 0.f;
    int cnt = 0;
    for (int ii = beg; ii < end; ii++) {
        int eid = csr_eid[ii];
        if (eid < E_) { s += edge_attr[(size_t)eid * DIM_ED + c]; cnt++; }
    }
    ea_mean[(size_t)node * DIM_ED + c] = s / fmaxf((float)cnt, 1.0f);
}

// ---------------------------------------------------------------------------
// in_proj: h = relu(x @ W0 + b0)
// ---------------------------------------------------------------------------
__global__ __launch_bounds__(128) void in_proj_kernel(
    const float* __restrict__ x, const float* __restrict__ W0, const float* __restrict__ b0,
    float* __restrict__ h) {
    int nb = blockIdx.x * 8;
    __shared__ float xs[8][DIM_IN];
    int tid = threadIdx.x;  // 128
    for (int i = tid; i < 8 * DIM_IN; i += 128) xs[i >> 6][i & 63] = x[(size_t)nb * DIM_IN + i];
    __syncthreads();
    float acc[8];
    float bias = b0[tid];
    #pragma unroll
    for (int j = 0; j < 8; j++) acc[j] = bias;
    for (int k = 0; k < DIM_IN; k++) {
        float w = W0[k * DIM_H + tid];
        #pragma unroll
        for (int j = 0; j < 8; j++) acc[j] += xs[j][k] * w;
    }
    #pragma unroll
    for (int j = 0; j < 8; j++) h[(size_t)(nb + j) * DIM_H + tid] = fmaxf(acc[j], 0.0f);
}

// ---------------------------------------------------------------------------
// node projections: xl = h@Wl+bl, xr = h@Wr+br
// ---------------------------------------------------------------------------
__global__ __launch_bounds__(256) void node_proj_kernel(
    const float* __restrict__ h, const float* __restrict__ Wl, const float* __restrict__ bl,
    const float* __restrict__ Wr, const float* __restrict__ br,
    float* __restrict__ xl, float* __restrict__ xr) {
    int nb = blockIdx.x * 8;
    __shared__ float hs[8][DIM_H];
    int tid = threadIdx.x;  // 256
    for (int i = tid; i < 8 * DIM_H; i += 256) hs[i >> 7][i & 127] = h[(size_t)nb * DIM_H + i];
    __syncthreads();
    float accL[8], accR[8];
    float bL = bl[tid], bR = br[tid];
    #pragma unroll
    for (int j = 0; j < 8; j++) { accL[j] = bL; accR[j] = bR; }
    for (int k = 0; k < DIM_H; k++) {
        float wl = Wl[k * 256 + tid];
        float wr = Wr[k * 256 + tid];
        #pragma unroll
        for (int j = 0; j < 8; j++) {
            accL[j] += hs[j][k] * wl;
            accR[j] += hs[j][k] * wr;
        }
    }
    #pragma unroll
    for (int j = 0; j < 8; j++) {
        xl[(size_t)(nb + j) * 256 + tid] = accL[j];
        xr[(size_t)(nb + j) * 256 + tid] = accR[j];
    }
}

// ---------------------------------------------------------------------------
// Fused GATv2 attention + aggregation.
// 2 waves per target node, 2 independent online-softmax states per wave.
// amdgpu_waves_per_eu(3,3): VGPR budget ~168 so the 64-float Wcol table
// stays register-resident (R6 post-mortem: min-waves hint caused a 64-VGPR
// clamp -> Wcol spilled to scratch -> 4 GB fetch / 2 GB write / 5x slowdown).
// ---------------------------------------------------------------------------
__global__ __attribute__((amdgpu_waves_per_eu(3, 3))) __launch_bounds__(256)
void gat_attn_kernel(
    const float* __restrict__ xl, const float* __restrict__ xr,
    const float* __restrict__ edge_attr, const float* __restrict__ ea_mean,
    const int* __restrict__ csr_src, const int* __restrict__ csr_eid,
    const int* __restrict__ csr_off,
    const float* __restrict__ We, const float* __restrict__ att, const float* __restrict__ bconv,
    float* __restrict__ h_new, int n, int E_) {
    int tid = threadIdx.x;
    int wave = tid >> 6, lane = tid & 63;
    int w2 = wave >> 1, sub = wave & 1;
    int t = blockIdx.x * 2 + w2;  // grid = n/2 exactly (n even), no guard needed
    int c0 = lane * 4;

    float4 Wcol[DIM_ED];
    #pragma unroll
    for (int k = 0; k < DIM_ED; k++) Wcol[k] = *(const float4*)(We + k * 256 + c0);
    float4 attv = *(const float4*)(att + c0);
    float4 xrt = *(const float4*)(xr + (size_t)t * 256 + c0);

    float4 accA = {0.f, 0.f, 0.f, 0.f}, accB = {0.f, 0.f, 0.f, 0.f};
    float dA = 0.f, dB = 0.f;
    float mA = NEG_INF, mB = NEG_INF;

    int beg = csr_off[t], end = csr_off[t + 1];

    for (int ii = beg + sub; ii < end; ii += 4) {
        int jj = ii + 2;
        bool hasB = (jj < end);       // wave-uniform
        int jc = hasB ? jj : ii;
        // issue all loads for both edges up front
        int sA = csr_src[ii];
        int sB = csr_src[jc];
        int eA = csr_eid[ii];
        int eB = csr_eid[jc];
        const float* eaA = (eA < E_) ? edge_attr + (size_t)eA * DIM_ED
                                     : ea_mean + (size_t)t * DIM_ED;
        const float* eaB = (eB < E_) ? edge_attr + (size_t)eB * DIM_ED
                                     : ea_mean + (size_t)t * DIM_ED;
        float4 xjA = *(const float4*)(xl + (size_t)sA * 256 + c0);
        float4 xjB = *(const float4*)(xl + (size_t)sB * 256 + c0);

        // edge projections, chunked to limit live registers
        float4 efA = {0.f, 0.f, 0.f, 0.f}, efB = {0.f, 0.f, 0.f, 0.f};
        #pragma unroll
        for (int q = 0; q < 4; q++) {
            float4 a4 = *(const float4*)(eaA + q * 4);
            float4 b4 = *(const float4*)(eaB + q * 4);
            float av[4] = {a4.x, a4.y, a4.z, a4.w};
            float bv[4] = {b4.x, b4.y, b4.z, b4.w};
            #pragma unroll
            for (int r = 0; r < 4; r++) {
                float4 w = Wcol[q * 4 + r];
                efA.x += av[r] * w.x; efA.y += av[r] * w.y;
                efA.z += av[r] * w.z; efA.w += av[r] * w.w;
                efB.x += bv[r] * w.x; efB.y += bv[r] * w.y;
                efB.z += bv[r] * w.z; efB.w += bv[r] * w.w;
            }
        }

        float a0 = xjA.x + xrt.x + efA.x; a0 = (a0 > 0.f) ? a0 : NEG_SLOPE * a0;
        float a1 = xjA.y + xrt.y + efA.y; a1 = (a1 > 0.f) ? a1 : NEG_SLOPE * a1;
        float a2 = xjA.z + xrt.z + efA.z; a2 = (a2 > 0.f) ? a2 : NEG_SLOPE * a2;
        float a3 = xjA.w + xrt.w + efA.w; a3 = (a3 > 0.f) ? a3 : NEG_SLOPE * a3;
        float lA = attv.x * a0 + attv.y * a1 + attv.z * a2 + attv.w * a3;
        float b0_ = xjB.x + xrt.x + efB.x; b0_ = (b0_ > 0.f) ? b0_ : NEG_SLOPE * b0_;
        float b1_ = xjB.y + xrt.y + efB.y; b1_ = (b1_ > 0.f) ? b1_ : NEG_SLOPE * b1_;
        float b2_ = xjB.z + xrt.z + efB.z; b2_ = (b2_ > 0.f) ? b2_ : NEG_SLOPE * b2_;
        float b3_ = xjB.w + xrt.w + efB.w; b3_ = (b3_ > 0.f) ? b3_ : NEG_SLOPE * b3_;
        float lB = attv.x * b0_ + attv.y * b1_ + attv.z * b2_ + attv.w * b3_;

        // interleaved 32-lane reductions (two independent chains)
        #pragma unroll
        for (int d = 1; d < 32; d <<= 1) {
            lA += __shfl_xor(lA, d, 64);
            lB += __shfl_xor(lB, d, 64);
        }

        // online softmax update, state A (single exp)
        {
            float mnew = fmaxf(mA, lA);
            float e = __expf(fminf(mA - lA, lA - mA));  // exp(-|diff|); -inf-safe
            bool nm = lA > mA;
            float scale = nm ? e : 1.f;
            float p = nm ? 1.f : e;
            dA = dA * scale + p;
            accA.x = accA.x * scale + p * xjA.x;
            accA.y = accA.y * scale + p * xjA.y;
            accA.z = accA.z * scale + p * xjA.z;
            accA.w = accA.w * scale + p * xjA.w;
            mA = mnew;
        }
        if (hasB) {
            float mnew = fmaxf(mB, lB);
            float e = __expf(fminf(mB - lB, lB - mB));
            bool nm = lB > mB;
            float scale = nm ? e : 1.f;
            float p = nm ? 1.f : e;
            dB = dB * scale + p;
            accB.x = accB.x * scale + p * xjB.x;
            accB.y = accB.y * scale + p * xjB.y;
            accB.z = accB.z * scale + p * xjB.z;
            accB.w = accB.w * scale + p * xjB.w;
            mB = mnew;
        }
    }

    // merge state B into A (exact)
    {
        float mW = fmaxf(mA, mB);
        float e1 = (mA > NEG_INF) ? __expf(mA - mW) : 0.f;
        float e2 = (mB > NEG_INF) ? __expf(mB - mW) : 0.f;
        dA = dA * e1 + dB * e2;
        accA.x = accA.x * e1 + accB.x * e2;
        accA.y = accA.y * e1 + accB.y * e2;
        accA.z = accA.z * e1 + accB.z * e2;
        accA.w = accA.w * e1 + accB.w * e2;
        mA = mW;
    }

    // cross-wave merge via LDS (sub 1 -> sub 0)
    __shared__ float red[2][64][8];
    if (sub == 1) {
        red[w2][lane][0] = accA.x;
        red[w2][lane][1] = accA.y;
        red[w2][lane][2] = accA.z;
        red[w2][lane][3] = accA.w;
        red[w2][lane][4] = mA;
        red[w2][lane][5] = dA;
    }
    __syncthreads();
    if (sub == 0) {
        float m2 = red[w2][lane][4];
        float d2 = red[w2][lane][5];
        float mF = fmaxf(mA, m2);           // mA finite (wave 0 owns slot beg)
        float e1 = __expf(mA - mF);
        float e2 = (m2 > NEG_INF) ? __expf(m2 - mF) : 0.f;
        float dF = dA * e1 + d2 * e2;
        float fx = accA.x * e1 + red[w2][lane][0] * e2;
        float fy = accA.y * e1 + red[w2][lane][1] * e2;
        float fz = accA.z * e1 + red[w2][lane][2] * e2;
        float fw = accA.w * e1 + red[w2][lane][3] * e2;
        float inv = 1.0f / dF;
        float o0 = fx * inv, o1 = fy * inv, o2 = fz * inv, o3 = fw * inv;
        // head mean: pair with lane^32 (same channel, other head)
        float u0 = 0.5f * (o0 + __shfl_xor(o0, 32, 64));
        float u1 = 0.5f * (o1 + __shfl_xor(o1, 32, 64));
        float u2 = 0.5f * (o2 + __shfl_xor(o2, 32, 64));
        float u3 = 0.5f * (o3 + __shfl_xor(o3, 32, 64));
        if (lane < 32) {
            float4 bc = *(const float4*)(bconv + c0);
            float4 ov;
            ov.x = fmaxf(u0 + bc.x, 0.f);
            ov.y = fmaxf(u1 + bc.y, 0.f);
            ov.z = fmaxf(u2 + bc.z, 0.f);
            ov.w = fmaxf(u3 + bc.w, 0.f);
            *(float4*)(h_new + (size_t)t * DIM_H + c0) = ov;
        }
    }
}

// ---------------------------------------------------------------------------
// decoder: out = sigmoid(relu(h@W1+b1)@W2+b2)
// ---------------------------------------------------------------------------
__global__ __launch_bounds__(128) void decoder_kernel(
    const float* __restrict__ h, const float* __restrict__ W1, const float* __restrict__ b1,
    const float* __restrict__ W2, const float* __restrict__ b2, float* __restrict__ out) {
    int nb = blockIdx.x * 4;
    __shared__ float hs[4][DIM_H];
    __shared__ float hid[4][DIM_H];
    int tid = threadIdx.x;  // 128
    for (int i = tid; i < 4 * DIM_H; i += 128) hs[i >> 7][i & 127] = h[(size_t)nb * DIM_H + i];
    __syncthreads();
    float acc[4];
    float bias = b1[tid];
    #pragma unroll
    for (int j = 0; j < 4; j++) acc[j] = bias;
    for (int k = 0; k < DIM_H; k++) {
        float w = W1[k * DIM_H + tid];
        #pragma unroll
        for (int j = 0; j < 4; j++) acc[j] += hs[j][k] * w;
    }
    #pragma unroll
    for (int j = 0; j < 4; j++) hid[j][tid] = fmaxf(acc[j], 0.0f);
    __syncthreads();
    int node = tid >> 5, oc = tid & 31;
    float a = b2[oc];
    for (int k = 0; k < DIM_H; k++) a += hid[node][k] * W2[k * DIM_OUT + oc];
    out[(size_t)(nb + node) * DIM_OUT + oc] = 1.0f / (1.0f + __expf(-a));
}

// ---------------------------------------------------------------------------
extern "C" void kernel_launch(void* const* d_in, const int* in_sizes, int n_in,
                              void* d_out, int out_size, void* d_ws, size_t ws_size,
                              hipStream_t stream) {
    const float* x         = (const float*)d_in[0];
    const int*   edge_index= (const int*)  d_in[1];
    const float* edge_attr = (const float*)d_in[2];
    const float* W0        = (const float*)d_in[3];
    const float* b0        = (const float*)d_in[4];
    const float* Wl        = (const float*)d_in[5];
    const float* bl        = (const float*)d_in[6];
    const float* Wr        = (const float*)d_in[7];
    const float* br        = (const float*)d_in[8];
    const float* We        = (const float*)d_in[9];
    const float* att       = (const float*)d_in[10];
    const float* bconv     = (const float*)d_in[11];
    const float* W1        = (const float*)d_in[12];
    const float* b1        = (const float*)d_in[13];
    const float* W2        = (const float*)d_in[14];
    const float* b2        = (const float*)d_in[15];
    float* out = (float*)d_out;

    const int N_ = N_NODES, E_ = N_EDGES;
    const int* src = edge_index;       // edge_index[0]
    const int* tgt = edge_index + E_;  // edge_index[1]

    char* ws = (char*)d_ws;
    size_t o = 0;
    auto alloc = [&](size_t bytes) -> void* {
        void* p = ws + o;
        o += (bytes + 255) & ~(size_t)255;
        return p;
    };
    float* h0      = (float*)alloc((size_t)N_ * DIM_H * 4);
    float* h1      = (float*)alloc((size_t)N_ * DIM_H * 4);
    float* xl      = (float*)alloc((size_t)N_ * 256 * 4);
    float* xr      = (float*)alloc((size_t)N_ * 256 * 4);
    float* ea_mean = (float*)alloc((size_t)N_ * DIM_ED * 4);
    int*   deg     = (int*)alloc((size_t)N_ * 4);
    int*   off     = (int*)alloc((size_t)(N_ + 1) * 4);
    int*   cursor  = (int*)alloc((size_t)N_ * 4);
    int*   eid     = (int*)alloc((size_t)(E_ + N_) * 4);
    int*   csrc    = (int*)alloc((size_t)(E_ + N_) * 4);

    hipMemsetAsync(deg, 0, (size_t)N_ * 4, stream);
    hipMemsetAsync(cursor, 0, (size_t)N_ * 4, stream);

    deg_kernel<<<(E_ + 255) / 256, 256, 0, stream>>>(tgt, deg, E_);
    scan_kernel<<<1, 1024, 0, stream>>>(deg, off, N_);
    scatter_kernel<<<(E_ + N_ + 255) / 256, 256, 0, stream>>>(tgt, src, off, cursor, eid, csrc, E_, N_);
    ea_mean_kernel<<<(N_ * DIM_ED + 255) / 256, 256, 0, stream>>>(edge_attr, eid, off, ea_mean, N_, E_);

    in_proj_kernel<<<N_ / 8, 128, 0, stream>>>(x, W0, b0, h0);

    float* hc = h0;
    float* hn = h1;
    for (int l = 0; l < 3; l++) {
        node_proj_kernel<<<N_ / 8, 256, 0, stream>>>(
            hc, Wl + (size_t)l * DIM_H * 256, bl + (size_t)l * 256,
            Wr + (size_t)l * DIM_H * 256, br + (size_t)l * 256, xl, xr);
        gat_attn_kernel<<<N_ / 2, 256, 0, stream>>>(
            xl, xr, edge_attr, ea_mean, csrc, eid, off,
            We + (size_t)l * DIM_ED * 256, att + (size_t)l * 256, bconv + (size_t)l * DIM_H,
            hn, N_, E_);
        float* tswap = hc; hc = hn; hn = tswap;
    }
    decoder_kernel<<<N_ / 4, 128, 0, stream>>>(hc, W1, b1, W2, b2, out);
}

// Round 10
// 1774.811 us; speedup vs baseline: 3.0081x; 1.6300x over previous
//
#include <hip/hip_runtime.h>
#include <hip/hip_bf16.h>

#define N_NODES 40000
#define N_EDGES 640000
#define DIM_IN 64
#define DIM_H 128
#define DIM_OUT 32
#define DIM_ED 16
#define HEADS 2
#define NEG_SLOPE 0.2f
#define NEG_INF (-__builtin_inff())

// ---------------------------------------------------------------------------
// degree count (1 int atomic per edge)
// ---------------------------------------------------------------------------
__global__ void deg_kernel(const int* __restrict__ tgt, int* __restrict__ deg, int E_) {
    int e = blockIdx.x * 256 + threadIdx.x;
    if (e >= E_) return;
    atomicAdd(&deg[tgt[e]], 1);
}

// ---------------------------------------------------------------------------
// exclusive scan of (deg[i]+1) -> off[0..n]; wave-shuffle scan
// ---------------------------------------------------------------------------
__global__ __launch_bounds__(1024) void scan_kernel(const int* __restrict__ deg,
                                                    int* __restrict__ off, int n) {
    __shared__ int wsum[16];
    __shared__ int carry_s;
    int tid = threadIdx.x;
    int wv = tid >> 6, ln = tid & 63;
    if (tid == 0) carry_s = 0;
    __syncthreads();
    for (int base = 0; base < n; base += 1024) {
        int i = base + tid;
        int v = (i < n) ? (deg[i] + 1) : 0;  // +1 = self loop
        int s = v;
        #pragma unroll
        for (int d = 1; d < 64; d <<= 1) {
            int u = __shfl_up(s, d, 64);
            if (ln >= d) s += u;
        }
        if (ln == 63) wsum[wv] = s;
        __syncthreads();
        int woff = 0;
        #pragma unroll
        for (int w = 0; w < 16; w++) woff += (w < wv) ? wsum[w] : 0;
        int carry = carry_s;
        if (i < n) off[i] = carry + woff + s - v;  // exclusive
        __syncthreads();
        if (tid == 1023) carry_s = carry + woff + s;
        __syncthreads();
    }
    if (tid == 0) off[n] = carry_s;
}

// scatter edge id AND source node id (kills one pointer-chase level in attn)
__global__ void scatter_kernel(const int* __restrict__ tgt, const int* __restrict__ src,
                               const int* __restrict__ off, int* __restrict__ cursor,
                               int* __restrict__ eid, int* __restrict__ csrc, int E_, int n) {
    int e = blockIdx.x * 256 + threadIdx.x;
    if (e >= E_ + n) return;
    int t, s;
    if (e < E_) { t = tgt[e]; s = src[e]; }
    else        { t = e - E_; s = e - E_; }
    int pos = atomicAdd(&cursor[t], 1);
    int slot = off[t] + pos;
    eid[slot] = e;
    csrc[slot] = s;
}

// ---------------------------------------------------------------------------
// ea_mean from CSR: 16 lanes per node, one channel each; no atomics
// ---------------------------------------------------------------------------
__global__ __launch_bounds__(256) void ea_mean_kernel(
    const float* __restrict__ edge_attr, const int* __restrict__ csr_eid,
    const int* __restrict__ csr_off, float* __restrict__ ea_mean, int n, int E_) {
    int tid = blockIdx.x * 256 + threadIdx.x;
    int node = tid >> 4;
    int c = tid & 15;
    if (node >= n) return;
    int beg = csr_off[node], end = csr_off[node + 1];
    float s = 0.f;
    int cnt = 0;
    for (int ii = beg; ii < end; ii++) {
        int eid = csr_eid[ii];
        if (eid < E_) { s += edge_attr[(size_t)eid * DIM_ED + c]; cnt++; }
    }
    ea_mean[(size_t)node * DIM_ED + c] = s / fmaxf((float)cnt, 1.0f);
}

// ---------------------------------------------------------------------------
// in_proj: h = relu(x @ W0 + b0)
// ---------------------------------------------------------------------------
__global__ __launch_bounds__(128) void in_proj_kernel(
    const float* __restrict__ x, const float* __restrict__ W0, const float* __restrict__ b0,
    float* __restrict__ h) {
    int nb = blockIdx.x * 8;
    __shared__ float xs[8][DIM_IN];
    int tid = threadIdx.x;  // 128
    for (int i = tid; i < 8 * DIM_IN; i += 128) xs[i >> 6][i & 63] = x[(size_t)nb * DIM_IN + i];
    __syncthreads();
    float acc[8];
    float bias = b0[tid];
    #pragma unroll
    for (int j = 0; j < 8; j++) acc[j] = bias;
    for (int k = 0; k < DIM_IN; k++) {
        float w = W0[k * DIM_H + tid];
        #pragma unroll
        for (int j = 0; j < 8; j++) acc[j] += xs[j][k] * w;
    }
    #pragma unroll
    for (int j = 0; j < 8; j++) h[(size_t)(nb + j) * DIM_H + tid] = fmaxf(acc[j], 0.0f);
}

// ---------------------------------------------------------------------------
// node projections: xl = h@Wl+bl, xr = h@Wr+br
// ---------------------------------------------------------------------------
__global__ __launch_bounds__(256) void node_proj_kernel(
    const float* __restrict__ h, const float* __restrict__ Wl, const float* __restrict__ bl,
    const float* __restrict__ Wr, const float* __restrict__ br,
    float* __restrict__ xl, float* __restrict__ xr) {
    int nb = blockIdx.x * 8;
    __shared__ float hs[8][DIM_H];
    int tid = threadIdx.x;  // 256
    for (int i = tid; i < 8 * DIM_H; i += 256) hs[i >> 7][i & 127] = h[(size_t)nb * DIM_H + i];
    __syncthreads();
    float accL[8], accR[8];
    float bL = bl[tid], bR = br[tid];
    #pragma unroll
    for (int j = 0; j < 8; j++) { accL[j] = bL; accR[j] = bR; }
    for (int k = 0; k < DIM_H; k++) {
        float wl = Wl[k * 256 + tid];
        float wr = Wr[k * 256 + tid];
        #pragma unroll
        for (int j = 0; j < 8; j++) {
            accL[j] += hs[j][k] * wl;
            accR[j] += hs[j][k] * wr;
        }
    }
    #pragma unroll
    for (int j = 0; j < 8; j++) {
        xl[(size_t)(nb + j) * 256 + tid] = accL[j];
        xr[(size_t)(nb + j) * 256 + tid] = accR[j];
    }
}

// ---------------------------------------------------------------------------
// Fused GATv2 attention + aggregation.
// 2 waves per target node, 2 independent online-softmax states per wave
// (4 independent chains hide gather + softmax latency).
// We staged in LDS (16 KB/block) and read per-edge via ds_read_b128:
// R6/R7 post-mortem showed a 64-float per-lane Wcol register table spills
// to scratch regardless of waves_per_eu hints (R6: 4 GB, R7: 740 MB scratch
// traffic). LDS reads serve both A and B edges; per-lane state ~50 VGPRs.
// ---------------------------------------------------------------------------
__global__ __launch_bounds__(256) void gat_attn_kernel(
    const float* __restrict__ xl, const float* __restrict__ xr,
    const float* __restrict__ edge_attr, const float* __restrict__ ea_mean,
    const int* __restrict__ csr_src, const int* __restrict__ csr_eid,
    const int* __restrict__ csr_off,
    const float* __restrict__ We, const float* __restrict__ att, const float* __restrict__ bconv,
    float* __restrict__ h_new, int n, int E_) {
    int tid = threadIdx.x;
    int wave = tid >> 6, lane = tid & 63;
    int w2 = wave >> 1, sub = wave & 1;
    int t = blockIdx.x * 2 + w2;  // grid = n/2 exactly (n even)
    int c0 = lane * 4;

    // stage We[16][256] into LDS (4 float4 per thread)
    __shared__ float We_s[DIM_ED][256];
    #pragma unroll
    for (int i = 0; i < 4; i++) {
        int idx = tid + i * 256;  // element group
        *(float4*)(&We_s[idx >> 6][(idx & 63) * 4] ) = *(const float4*)(We + idx * 4);
    }
    __syncthreads();

    float4 attv = *(const float4*)(att + c0);
    float4 xrt = *(const float4*)(xr + (size_t)t * 256 + c0);

    float4 accA = {0.f, 0.f, 0.f, 0.f}, accB = {0.f, 0.f, 0.f, 0.f};
    float dA = 0.f, dB = 0.f;
    float mA = NEG_INF, mB = NEG_INF;

    int beg = csr_off[t], end = csr_off[t + 1];

    for (int ii = beg + sub; ii < end; ii += 4) {
        int jj = ii + 2;
        bool hasB = (jj < end);       // wave-uniform
        int jc = hasB ? jj : ii;
        // issue all loads for both edges up front
        int sA = csr_src[ii];
        int sB = csr_src[jc];
        int eA = csr_eid[ii];
        int eB = csr_eid[jc];
        const float* eaA = (eA < E_) ? edge_attr + (size_t)eA * DIM_ED
                                     : ea_mean + (size_t)t * DIM_ED;
        const float* eaB = (eB < E_) ? edge_attr + (size_t)eB * DIM_ED
                                     : ea_mean + (size_t)t * DIM_ED;
        float4 xjA = *(const float4*)(xl + (size_t)sA * 256 + c0);
        float4 xjB = *(const float4*)(xl + (size_t)sB * 256 + c0);

        // edge projections; We columns from LDS, each read shared by A and B
        float4 efA = {0.f, 0.f, 0.f, 0.f}, efB = {0.f, 0.f, 0.f, 0.f};
        #pragma unroll
        for (int q = 0; q < 4; q++) {
            float4 a4 = *(const float4*)(eaA + q * 4);
            float4 b4 = *(const float4*)(eaB + q * 4);
            float av[4] = {a4.x, a4.y, a4.z, a4.w};
            float bv[4] = {b4.x, b4.y, b4.z, b4.w};
            #pragma unroll
            for (int r = 0; r < 4; r++) {
                float4 w = *(const float4*)(&We_s[q * 4 + r][c0]);
                efA.x += av[r] * w.x; efA.y += av[r] * w.y;
                efA.z += av[r] * w.z; efA.w += av[r] * w.w;
                efB.x += bv[r] * w.x; efB.y += bv[r] * w.y;
                efB.z += bv[r] * w.z; efB.w += bv[r] * w.w;
            }
        }

        float a0 = xjA.x + xrt.x + efA.x; a0 = (a0 > 0.f) ? a0 : NEG_SLOPE * a0;
        float a1 = xjA.y + xrt.y + efA.y; a1 = (a1 > 0.f) ? a1 : NEG_SLOPE * a1;
        float a2 = xjA.z + xrt.z + efA.z; a2 = (a2 > 0.f) ? a2 : NEG_SLOPE * a2;
        float a3 = xjA.w + xrt.w + efA.w; a3 = (a3 > 0.f) ? a3 : NEG_SLOPE * a3;
        float lA = attv.x * a0 + attv.y * a1 + attv.z * a2 + attv.w * a3;
        float b0_ = xjB.x + xrt.x + efB.x; b0_ = (b0_ > 0.f) ? b0_ : NEG_SLOPE * b0_;
        float b1_ = xjB.y + xrt.y + efB.y; b1_ = (b1_ > 0.f) ? b1_ : NEG_SLOPE * b1_;
        float b2_ = xjB.z + xrt.z + efB.z; b2_ = (b2_ > 0.f) ? b2_ : NEG_SLOPE * b2_;
        float b3_ = xjB.w + xrt.w + efB.w; b3_ = (b3_ > 0.f) ? b3_ : NEG_SLOPE * b3_;
        float lB = attv.x * b0_ + attv.y * b1_ + attv.z * b2_ + attv.w * b3_;

        // interleaved 32-lane reductions (two independent chains)
        #pragma unroll
        for (int d = 1; d < 32; d <<= 1) {
            lA += __shfl_xor(lA, d, 64);
            lB += __shfl_xor(lB, d, 64);
        }

        // online softmax update, state A (single exp)
        {
            float mnew = fmaxf(mA, lA);
            float e = __expf(fminf(mA - lA, lA - mA));  // exp(-|diff|); -inf-safe
            bool nm = lA > mA;
            float scale = nm ? e : 1.f;
            float p = nm ? 1.f : e;
            dA = dA * scale + p;
            accA.x = accA.x * scale + p * xjA.x;
            accA.y = accA.y * scale + p * xjA.y;
            accA.z = accA.z * scale + p * xjA.z;
            accA.w = accA.w * scale + p * xjA.w;
            mA = mnew;
        }
        if (hasB) {
            float mnew = fmaxf(mB, lB);
            float e = __expf(fminf(mB - lB, lB - mB));
            bool nm = lB > mB;
            float scale = nm ? e : 1.f;
            float p = nm ? 1.f : e;
            dB = dB * scale + p;
            accB.x = accB.x * scale + p * xjB.x;
            accB.y = accB.y * scale + p * xjB.y;
            accB.z = accB.z * scale + p * xjB.z;
            accB.w = accB.w * scale + p * xjB.w;
            mB = mnew;
        }
    }

    // merge state B into A (exact)
    {
        float mW = fmaxf(mA, mB);
        float e1 = (mA > NEG_INF) ? __expf(mA - mW) : 0.f;
        float e2 = (mB > NEG_INF) ? __expf(mB - mW) : 0.f;
        dA = dA * e1 + dB * e2;
        accA.x = accA.x * e1 + accB.x * e2;
        accA.y = accA.y * e1 + accB.y * e2;
        accA.z = accA.z * e1 + accB.z * e2;
        accA.w = accA.w * e1 + accB.w * e2;
        mA = mW;
    }

    // cross-wave merge via LDS (sub 1 -> sub 0)
    __shared__ float red[2][64][8];
    if (sub == 1) {
        red[w2][lane][0] = accA.x;
        red[w2][lane][1] = accA.y;
        red[w2][lane][2] = accA.z;
        red[w2][lane][3] = accA.w;
        red[w2][lane][4] = mA;
        red[w2][lane][5] = dA;
    }
    __syncthreads();
    if (sub == 0) {
        float m2 = red[w2][lane][4];
        float d2 = red[w2][lane][5];
        float mF = fmaxf(mA, m2);           // mA finite (wave 0 owns slot beg)
        float e1 = __expf(mA - mF);
        float e2 = (m2 > NEG_INF) ? __expf(m2 - mF) : 0.f;
        float dF = dA * e1 + d2 * e2;
        float fx = accA.x * e1 + red[w2][lane][0] * e2;
        float fy = accA.y * e1 + red[w2][lane][1] * e2;
        float fz = accA.z * e1 + red[w2][lane][2] * e2;
        float fw = accA.w * e1 + red[w2][lane][3] * e2;
        float inv = 1.0f / dF;
        float o0 = fx * inv, o1 = fy * inv, o2 = fz * inv, o3 = fw * inv;
        // head mean: pair with lane^32 (same channel, other head)
        float u0 = 0.5f * (o0 + __shfl_xor(o0, 32, 64));
        float u1 = 0.5f * (o1 + __shfl_xor(o1, 32, 64));
        float u2 = 0.5f * (o2 + __shfl_xor(o2, 32, 64));
        float u3 = 0.5f * (o3 + __shfl_xor(o3, 32, 64));
        if (lane < 32) {
            float4 bc = *(const float4*)(bconv + c0);
            float4 ov;
            ov.x = fmaxf(u0 + bc.x, 0.f);
            ov.y = fmaxf(u1 + bc.y, 0.f);
            ov.z = fmaxf(u2 + bc.z, 0.f);
            ov.w = fmaxf(u3 + bc.w, 0.f);
            *(float4*)(h_new + (size_t)t * DIM_H + c0) = ov;
        }
    }
}

// ---------------------------------------------------------------------------
// decoder: out = sigmoid(relu(h@W1+b1)@W2+b2)
// ---------------------------------------------------------------------------
__global__ __launch_bounds__(128) void decoder_kernel(
    const float* __restrict__ h, const float* __restrict__ W1, const float* __restrict__ b1,
    const float* __restrict__ W2, const float* __restrict__ b2, float* __restrict__ out) {
    int nb = blockIdx.x * 4;
    __shared__ float hs[4][DIM_H];
    __shared__ float hid[4][DIM_H];
    int tid = threadIdx.x;  // 128
    for (int i = tid; i < 4 * DIM_H; i += 128) hs[i >> 7][i & 127] = h[(size_t)nb * DIM_H + i];
    __syncthreads();
    float acc[4];
    float bias = b1[tid];
    #pragma unroll
    for (int j = 0; j < 4; j++) acc[j] = bias;
    for (int k = 0; k < DIM_H; k++) {
        float w = W1[k * DIM_H + tid];
        #pragma unroll
        for (int j = 0; j < 4; j++) acc[j] += hs[j][k] * w;
    }
    #pragma unroll
    for (int j = 0; j < 4; j++) hid[j][tid] = fmaxf(acc[j], 0.0f);
    __syncthreads();
    int node = tid >> 5, oc = tid & 31;
    float a = b2[oc];
    for (int k = 0; k < DIM_H; k++) a += hid[node][k] * W2[k * DIM_OUT + oc];
    out[(size_t)(nb + node) * DIM_OUT + oc] = 1.0f / (1.0f + __expf(-a));
}

// ---------------------------------------------------------------------------
extern "C" void kernel_launch(void* const* d_in, const int* in_sizes, int n_in,
                              void* d_out, int out_size, void* d_ws, size_t ws_size,
                              hipStream_t stream) {
    const float* x         = (const float*)d_in[0];
    const int*   edge_index= (const int*)  d_in[1];
    const float* edge_attr = (const float*)d_in[2];
    const float* W0        = (const float*)d_in[3];
    const float* b0        = (const float*)d_in[4];
    const float* Wl        = (const float*)d_in[5];
    const float* bl        = (const float*)d_in[6];
    const float* Wr        = (const float*)d_in[7];
    const float* br        = (const float*)d_in[8];
    const float* We        = (const float*)d_in[9];
    const float* att       = (const float*)d_in[10];
    const float* bconv     = (const float*)d_in[11];
    const float* W1        = (const float*)d_in[12];
    const float* b1        = (const float*)d_in[13];
    const float* W2        = (const float*)d_in[14];
    const float* b2        = (const float*)d_in[15];
    float* out = (float*)d_out;

    const int N_ = N_NODES, E_ = N_EDGES;
    const int* src = edge_index;       // edge_index[0]
    const int* tgt = edge_index + E_;  // edge_index[1]

    char* ws = (char*)d_ws;
    size_t o = 0;
    auto alloc = [&](size_t bytes) -> void* {
        void* p = ws + o;
        o += (bytes + 255) & ~(size_t)255;
        return p;
    };
    float* h0      = (float*)alloc((size_t)N_ * DIM_H * 4);
    float* h1      = (float*)alloc((size_t)N_ * DIM_H * 4);
    float* xl      = (float*)alloc((size_t)N_ * 256 * 4);
    float* xr      = (float*)alloc((size_t)N_ * 256 * 4);
    float* ea_mean = (float*)alloc((size_t)N_ * DIM_ED * 4);
    int*   deg     = (int*)alloc((size_t)N_ * 4);
    int*   off     = (int*)alloc((size_t)(N_ + 1) * 4);
    int*   cursor  = (int*)alloc((size_t)N_ * 4);
    int*   eid     = (int*)alloc((size_t)(E_ + N_) * 4);
    int*   csrc    = (int*)alloc((size_t)(E_ + N_) * 4);

    hipMemsetAsync(deg, 0, (size_t)N_ * 4, stream);
    hipMemsetAsync(cursor, 0, (size_t)N_ * 4, stream);

    deg_kernel<<<(E_ + 255) / 256, 256, 0, stream>>>(tgt, deg, E_);
    scan_kernel<<<1, 1024, 0, stream>>>(deg, off, N_);
    scatter_kernel<<<(E_ + N_ + 255) / 256, 256, 0, stream>>>(tgt, src, off, cursor, eid, csrc, E_, N_);
    ea_mean_kernel<<<(N_ * DIM_ED + 255) / 256, 256, 0, stream>>>(edge_attr, eid, off, ea_mean, N_, E_);

    in_proj_kernel<<<N_ / 8, 128, 0, stream>>>(x, W0, b0, h0);

    float* hc = h0;
    float* hn = h1;
    for (int l = 0; l < 3; l++) {
        node_proj_kernel<<<N_ / 8, 256, 0, stream>>>(
            hc, Wl + (size_t)l * DIM_H * 256, bl + (size_t)l * 256,
            Wr + (size_t)l * DIM_H * 256, br + (size_t)l * 256, xl, xr);
        gat_attn_kernel<<<N_ / 2, 256, 0, stream>>>(
            xl, xr, edge_attr, ea_mean, csrc, eid, off,
            We + (size_t)l * DIM_ED * 256, att + (size_t)l * 256, bconv + (size_t)l * DIM_H,
            hn, N_, E_);
        float* tswap = hc; hc = hn; hn = tswap;
    }
    decoder_kernel<<<N_ / 4, 128, 0, stream>>>(hc, W1, b1, W2, b2, out);
}

// Round 11
// 1415.703 us; speedup vs baseline: 3.7711x; 1.2537x over previous
//
#include <hip/hip_runtime.h>
#include <hip/hip_bf16.h>

#define N_NODES 40000
#define N_EDGES 640000
#define DIM_IN 64
#define DIM_H 128
#define DIM_OUT 32
#define DIM_ED 16
#define HEADS 2
#define NEG_SLOPE 0.2f
#define NEG_INF (-__builtin_inff())

// ---------------------------------------------------------------------------
// degree count (1 int atomic per edge)
// ---------------------------------------------------------------------------
__global__ void deg_kernel(const int* __restrict__ tgt, int* __restrict__ deg, int E_) {
    int e = blockIdx.x * 256 + threadIdx.x;
    if (e >= E_) return;
    atomicAdd(&deg[tgt[e]], 1);
}

// ---------------------------------------------------------------------------
// exclusive scan of (deg[i]+1) -> off[0..n]; wave-shuffle scan
// ---------------------------------------------------------------------------
__global__ __launch_bounds__(1024) void scan_kernel(const int* __restrict__ deg,
                                                    int* __restrict__ off, int n) {
    __shared__ int wsum[16];
    __shared__ int carry_s;
    int tid = threadIdx.x;
    int wv = tid >> 6, ln = tid & 63;
    if (tid == 0) carry_s = 0;
    __syncthreads();
    for (int base = 0; base < n; base += 1024) {
        int i = base + tid;
        int v = (i < n) ? (deg[i] + 1) : 0;  // +1 = self loop
        int s = v;
        #pragma unroll
        for (int d = 1; d < 64; d <<= 1) {
            int u = __shfl_up(s, d, 64);
            if (ln >= d) s += u;
        }
        if (ln == 63) wsum[wv] = s;
        __syncthreads();
        int woff = 0;
        #pragma unroll
        for (int w = 0; w < 16; w++) woff += (w < wv) ? wsum[w] : 0;
        int carry = carry_s;
        if (i < n) off[i] = carry + woff + s - v;  // exclusive
        __syncthreads();
        if (tid == 1023) carry_s = carry + woff + s;
        __syncthreads();
    }
    if (tid == 0) off[n] = carry_s;
}

// scatter edge id AND source node id (kills one pointer-chase level in attn)
__global__ void scatter_kernel(const int* __restrict__ tgt, const int* __restrict__ src,
                               const int* __restrict__ off, int* __restrict__ cursor,
                               int* __restrict__ eid, int* __restrict__ csrc, int E_, int n) {
    int e = blockIdx.x * 256 + threadIdx.x;
    if (e >= E_ + n) return;
    int t, s;
    if (e < E_) { t = tgt[e]; s = src[e]; }
    else        { t = e - E_; s = e - E_; }
    int pos = atomicAdd(&cursor[t], 1);
    int slot = off[t] + pos;
    eid[slot] = e;
    csrc[slot] = s;
}

// ---------------------------------------------------------------------------
// ea_mean from CSR: 16 lanes per node, one channel each; no atomics
// ---------------------------------------------------------------------------
__global__ __launch_bounds__(256) void ea_mean_kernel(
    const float* __restrict__ edge_attr, const int* __restrict__ csr_eid,
    const int* __restrict__ csr_off, float* __restrict__ ea_mean, int n, int E_) {
    int tid = blockIdx.x * 256 + threadIdx.x;
    int node = tid >> 4;
    int c = tid & 15;
    if (node >= n) return;
    int beg = csr_off[node], end = csr_off[node + 1];
    float s = 0.f;
    int cnt = 0;
    for (int ii = beg; ii < end; ii++) {
        int eid = csr_eid[ii];
        if (eid < E_) { s += edge_attr[(size_t)eid * DIM_ED + c]; cnt++; }
    }
    ea_mean[(size_t)node * DIM_ED + c] = s / fmaxf((float)cnt, 1.0f);
}

// ---------------------------------------------------------------------------
// in_proj: h = relu(x @ W0 + b0)
// ---------------------------------------------------------------------------
__global__ __launch_bounds__(128) void in_proj_kernel(
    const float* __restrict__ x, const float* __restrict__ W0, const float* __restrict__ b0,
    float* __restrict__ h) {
    int nb = blockIdx.x * 8;
    __shared__ float xs[8][DIM_IN];
    int tid = threadIdx.x;  // 128
    for (int i = tid; i < 8 * DIM_IN; i += 128) xs[i >> 6][i & 63] = x[(size_t)nb * DIM_IN + i];
    __syncthreads();
    float acc[8];
    float bias = b0[tid];
    #pragma unroll
    for (int j = 0; j < 8; j++) acc[j] = bias;
    for (int k = 0; k < DIM_IN; k++) {
        float w = W0[k * DIM_H + tid];
        #pragma unroll
        for (int j = 0; j < 8; j++) acc[j] += xs[j][k] * w;
    }
    #pragma unroll
    for (int j = 0; j < 8; j++) h[(size_t)(nb + j) * DIM_H + tid] = fmaxf(acc[j], 0.0f);
}

// ---------------------------------------------------------------------------
// node projections: xl = h@Wl+bl, xr = h@Wr+br
// ---------------------------------------------------------------------------
__global__ __launch_bounds__(256) void node_proj_kernel(
    const float* __restrict__ h, const float* __restrict__ Wl, const float* __restrict__ bl,
    const float* __restrict__ Wr, const float* __restrict__ br,
    float* __restrict__ xl, float* __restrict__ xr) {
    int nb = blockIdx.x * 8;
    __shared__ float hs[8][DIM_H];
    int tid = threadIdx.x;  // 256
    for (int i = tid; i < 8 * DIM_H; i += 256) hs[i >> 7][i & 127] = h[(size_t)nb * DIM_H + i];
    __syncthreads();
    float accL[8], accR[8];
    float bL = bl[tid], bR = br[tid];
    #pragma unroll
    for (int j = 0; j < 8; j++) { accL[j] = bL; accR[j] = bR; }
    for (int k = 0; k < DIM_H; k++) {
        float wl = Wl[k * 256 + tid];
        float wr = Wr[k * 256 + tid];
        #pragma unroll
        for (int j = 0; j < 8; j++) {
            accL[j] += hs[j][k] * wl;
            accR[j] += hs[j][k] * wr;
        }
    }
    #pragma unroll
    for (int j = 0; j < 8; j++) {
        xl[(size_t)(nb + j) * 256 + tid] = accL[j];
        xr[(size_t)(nb + j) * 256 + tid] = accR[j];
    }
}

// ---------------------------------------------------------------------------
// Fused GATv2 attention + aggregation, v3.
// 1 wave per node (4 nodes / 256-thread block), single online-softmax state,
// edges processed 4 at a time:
//  - one We_s[k] LDS read feeds 4 edges x 4 channels (4 KB LDS per edge,
//    half of R10's 8 KB -> LDS floor ~52 us/CU/layer)
//  - 4 gathers in flight per iteration (memory-level parallelism)
//  - ONE softmax max/rescale per 4 edges (exact: joint max reassociation)
//  - ea loaded float4-at-a-time inside the k-loop: only 16 live ea VGPRs
//    (R6 lesson: 64 live per-lane floats = spill)
// Low VGPR (~100) + no cross-wave merge -> more resident waves for latency.
// ---------------------------------------------------------------------------
__global__ __launch_bounds__(256) void gat_attn_kernel(
    const float* __restrict__ xl, const float* __restrict__ xr,
    const float* __restrict__ edge_attr, const float* __restrict__ ea_mean,
    const int* __restrict__ csr_src, const int* __restrict__ csr_eid,
    const int* __restrict__ csr_off,
    const float* __restrict__ We, const float* __restrict__ att, const float* __restrict__ bconv,
    float* __restrict__ h_new, int n, int E_) {
    int tid = threadIdx.x;
    int wave = tid >> 6, lane = tid & 63;
    int t = blockIdx.x * 4 + wave;  // grid = n/4 exactly
    int c0 = lane * 4;

    // stage We[16][256] into LDS (4 float4 per thread)
    __shared__ float We_s[DIM_ED][256];
    #pragma unroll
    for (int i = 0; i < 4; i++) {
        int idx = tid + i * 256;
        *(float4*)(&We_s[idx >> 6][(idx & 63) * 4]) = *(const float4*)(We + idx * 4);
    }
    __syncthreads();

    float4 attv = *(const float4*)(att + c0);
    float4 xrt  = *(const float4*)(xr + (size_t)t * 256 + c0);

    float4 acc = {0.f, 0.f, 0.f, 0.f};
    float dnm = 0.f;
    float m = NEG_INF;

    int beg = csr_off[t], end = csr_off[t + 1];

    for (int ii = beg; ii < end; ii += 4) {
        int c = end - ii; if (c > 4) c = 4;
        int i1 = ii + (1 < c ? 1 : 0);
        int i2 = ii + (2 < c ? 2 : 0);
        int i3 = ii + (3 < c ? 3 : 0);
        // issue all index + gather loads up front (4-deep MLP)
        int s0 = csr_src[ii], s1 = csr_src[i1], s2 = csr_src[i2], s3 = csr_src[i3];
        int e0 = csr_eid[ii], e1 = csr_eid[i1], e2 = csr_eid[i2], e3 = csr_eid[i3];
        const float* ea0 = (e0 < E_) ? edge_attr + (size_t)e0 * DIM_ED : ea_mean + (size_t)t * DIM_ED;
        const float* ea1 = (e1 < E_) ? edge_attr + (size_t)e1 * DIM_ED : ea_mean + (size_t)t * DIM_ED;
        const float* ea2 = (e2 < E_) ? edge_attr + (size_t)e2 * DIM_ED : ea_mean + (size_t)t * DIM_ED;
        const float* ea3 = (e3 < E_) ? edge_attr + (size_t)e3 * DIM_ED : ea_mean + (size_t)t * DIM_ED;
        float4 xj0 = *(const float4*)(xl + (size_t)s0 * 256 + c0);
        float4 xj1 = *(const float4*)(xl + (size_t)s1 * 256 + c0);
        float4 xj2 = *(const float4*)(xl + (size_t)s2 * 256 + c0);
        float4 xj3 = *(const float4*)(xl + (size_t)s3 * 256 + c0);

        // ef: k-outer loop, one LDS read per k serves 4 edges x 4 channels
        float4 ef0 = {0,0,0,0}, ef1 = {0,0,0,0}, ef2 = {0,0,0,0}, ef3 = {0,0,0,0};
        #pragma unroll
        for (int kq = 0; kq < 4; kq++) {
            float4 a0 = *(const float4*)(ea0 + kq * 4);
            float4 a1 = *(const float4*)(ea1 + kq * 4);
            float4 a2 = *(const float4*)(ea2 + kq * 4);
            float4 a3 = *(const float4*)(ea3 + kq * 4);
            float v0[4] = {a0.x, a0.y, a0.z, a0.w};
            float v1[4] = {a1.x, a1.y, a1.z, a1.w};
            float v2[4] = {a2.x, a2.y, a2.z, a2.w};
            float v3[4] = {a3.x, a3.y, a3.z, a3.w};
            #pragma unroll
            for (int r = 0; r < 4; r++) {
                float4 w = *(const float4*)(&We_s[kq * 4 + r][c0]);
                ef0.x += v0[r] * w.x; ef0.y += v0[r] * w.y; ef0.z += v0[r] * w.z; ef0.w += v0[r] * w.w;
                ef1.x += v1[r] * w.x; ef1.y += v1[r] * w.y; ef1.z += v1[r] * w.z; ef1.w += v1[r] * w.w;
                ef2.x += v2[r] * w.x; ef2.y += v2[r] * w.y; ef2.z += v2[r] * w.z; ef2.w += v2[r] * w.w;
                ef3.x += v3[r] * w.x; ef3.y += v3[r] * w.y; ef3.z += v3[r] * w.z; ef3.w += v3[r] * w.w;
            }
        }

        // logits (leaky-relu then dot with att), 4 edges
        float l0, l1, l2, l3;
        {
            float q0 = xj0.x + xrt.x + ef0.x; q0 = (q0 > 0.f) ? q0 : NEG_SLOPE * q0;
            float q1 = xj0.y + xrt.y + ef0.y; q1 = (q1 > 0.f) ? q1 : NEG_SLOPE * q1;
            float q2 = xj0.z + xrt.z + ef0.z; q2 = (q2 > 0.f) ? q2 : NEG_SLOPE * q2;
            float q3 = xj0.w + xrt.w + ef0.w; q3 = (q3 > 0.f) ? q3 : NEG_SLOPE * q3;
            l0 = attv.x * q0 + attv.y * q1 + attv.z * q2 + attv.w * q3;
        }
        {
            float q0 = xj1.x + xrt.x + ef1.x; q0 = (q0 > 0.f) ? q0 : NEG_SLOPE * q0;
            float q1 = xj1.y + xrt.y + ef1.y; q1 = (q1 > 0.f) ? q1 : NEG_SLOPE * q1;
            float q2 = xj1.z + xrt.z + ef1.z; q2 = (q2 > 0.f) ? q2 : NEG_SLOPE * q2;
            float q3 = xj1.w + xrt.w + ef1.w; q3 = (q3 > 0.f) ? q3 : NEG_SLOPE * q3;
            l1 = attv.x * q0 + attv.y * q1 + attv.z * q2 + attv.w * q3;
        }
        {
            float q0 = xj2.x + xrt.x + ef2.x; q0 = (q0 > 0.f) ? q0 : NEG_SLOPE * q0;
            float q1 = xj2.y + xrt.y + ef2.y; q1 = (q1 > 0.f) ? q1 : NEG_SLOPE * q1;
            float q2 = xj2.z + xrt.z + ef2.z; q2 = (q2 > 0.f) ? q2 : NEG_SLOPE * q2;
            float q3 = xj2.w + xrt.w + ef2.w; q3 = (q3 > 0.f) ? q3 : NEG_SLOPE * q3;
            l2 = attv.x * q0 + attv.y * q1 + attv.z * q2 + attv.w * q3;
        }
        {
            float q0 = xj3.x + xrt.x + ef3.x; q0 = (q0 > 0.f) ? q0 : NEG_SLOPE * q0;
            float q1 = xj3.y + xrt.y + ef3.y; q1 = (q1 > 0.f) ? q1 : NEG_SLOPE * q1;
            float q2 = xj3.z + xrt.z + ef3.z; q2 = (q2 > 0.f) ? q2 : NEG_SLOPE * q2;
            float q3 = xj3.w + xrt.w + ef3.w; q3 = (q3 > 0.f) ? q3 : NEG_SLOPE * q3;
            l3 = attv.x * q0 + attv.y * q1 + attv.z * q2 + attv.w * q3;
        }

        // 4 interleaved 32-lane reductions (per-head sum)
        #pragma unroll
        for (int d = 1; d < 32; d <<= 1) {
            l0 += __shfl_xor(l0, d, 64);
            l1 += __shfl_xor(l1, d, 64);
            l2 += __shfl_xor(l2, d, 64);
            l3 += __shfl_xor(l3, d, 64);
        }
        // tail: disable duplicate slots (p -> 0)
        if (1 >= c) l1 = NEG_INF;
        if (2 >= c) l2 = NEG_INF;
        if (3 >= c) l3 = NEG_INF;

        // batched online-softmax update (exact; one rescale per chunk)
        float lmax = fmaxf(fmaxf(l0, l1), fmaxf(l2, l3));
        float mnew = fmaxf(m, lmax);        // finite (l0 always real)
        float scale = __expf(m - mnew);     // m=-inf on first chunk -> 0
        float p0 = __expf(l0 - mnew);
        float p1 = __expf(l1 - mnew);
        float p2 = __expf(l2 - mnew);
        float p3 = __expf(l3 - mnew);
        dnm = dnm * scale + p0 + p1 + p2 + p3;
        acc.x = acc.x * scale + p0 * xj0.x + p1 * xj1.x + p2 * xj2.x + p3 * xj3.x;
        acc.y = acc.y * scale + p0 * xj0.y + p1 * xj1.y + p2 * xj2.y + p3 * xj3.y;
        acc.z = acc.z * scale + p0 * xj0.z + p1 * xj1.z + p2 * xj2.z + p3 * xj3.z;
        acc.w = acc.w * scale + p0 * xj0.w + p1 * xj1.w + p2 * xj2.w + p3 * xj3.w;
        m = mnew;
    }

    float inv = 1.0f / dnm;
    float o0 = acc.x * inv, o1 = acc.y * inv, o2 = acc.z * inv, o3 = acc.w * inv;
    // head mean: lane pairs with lane^32 (same channel, other head)
    float u0 = 0.5f * (o0 + __shfl_xor(o0, 32, 64));
    float u1 = 0.5f * (o1 + __shfl_xor(o1, 32, 64));
    float u2 = 0.5f * (o2 + __shfl_xor(o2, 32, 64));
    float u3 = 0.5f * (o3 + __shfl_xor(o3, 32, 64));
    if (lane < 32) {
        float4 bc = *(const float4*)(bconv + c0);
        float4 ov;
        ov.x = fmaxf(u0 + bc.x, 0.f);
        ov.y = fmaxf(u1 + bc.y, 0.f);
        ov.z = fmaxf(u2 + bc.z, 0.f);
        ov.w = fmaxf(u3 + bc.w, 0.f);
        *(float4*)(h_new + (size_t)t * DIM_H + c0) = ov;
    }
}

// ---------------------------------------------------------------------------
// decoder: out = sigmoid(relu(h@W1+b1)@W2+b2)
// ---------------------------------------------------------------------------
__global__ __launch_bounds__(128) void decoder_kernel(
    const float* __restrict__ h, const float* __restrict__ W1, const float* __restrict__ b1,
    const float* __restrict__ W2, const float* __restrict__ b2, float* __restrict__ out) {
    int nb = blockIdx.x * 4;
    __shared__ float hs[4][DIM_H];
    __shared__ float hid[4][DIM_H];
    int tid = threadIdx.x;  // 128
    for (int i = tid; i < 4 * DIM_H; i += 128) hs[i >> 7][i & 127] = h[(size_t)nb * DIM_H + i];
    __syncthreads();
    float acc[4];
    float bias = b1[tid];
    #pragma unroll
    for (int j = 0; j < 4; j++) acc[j] = bias;
    for (int k = 0; k < DIM_H; k++) {
        float w = W1[k * DIM_H + tid];
        #pragma unroll
        for (int j = 0; j < 4; j++) acc[j] += hs[j][k] * w;
    }
    #pragma unroll
    for (int j = 0; j < 4; j++) hid[j][tid] = fmaxf(acc[j], 0.0f);
    __syncthreads();
    int node = tid >> 5, oc = tid & 31;
    float a = b2[oc];
    for (int k = 0; k < DIM_H; k++) a += hid[node][k] * W2[k * DIM_OUT + oc];
    out[(size_t)(nb + node) * DIM_OUT + oc] = 1.0f / (1.0f + __expf(-a));
}

// ---------------------------------------------------------------------------
extern "C" void kernel_launch(void* const* d_in, const int* in_sizes, int n_in,
                              void* d_out, int out_size, void* d_ws, size_t ws_size,
                              hipStream_t stream) {
    const float* x         = (const float*)d_in[0];
    const int*   edge_index= (const int*)  d_in[1];
    const float* edge_attr = (const float*)d_in[2];
    const float* W0        = (const float*)d_in[3];
    const float* b0        = (const float*)d_in[4];
    const float* Wl        = (const float*)d_in[5];
    const float* bl        = (const float*)d_in[6];
    const float* Wr        = (const float*)d_in[7];
    const float* br        = (const float*)d_in[8];
    const float* We        = (const float*)d_in[9];
    const float* att       = (const float*)d_in[10];
    const float* bconv     = (const float*)d_in[11];
    const float* W1        = (const float*)d_in[12];
    const float* b1        = (const float*)d_in[13];
    const float* W2        = (const float*)d_in[14];
    const float* b2        = (const float*)d_in[15];
    float* out = (float*)d_out;

    const int N_ = N_NODES, E_ = N_EDGES;
    const int* src = edge_index;       // edge_index[0]
    const int* tgt = edge_index + E_;  // edge_index[1]

    char* ws = (char*)d_ws;
    size_t o = 0;
    auto alloc = [&](size_t bytes) -> void* {
        void* p = ws + o;
        o += (bytes + 255) & ~(size_t)255;
        return p;
    };
    float* h0      = (float*)alloc((size_t)N_ * DIM_H * 4);
    float* h1      = (float*)alloc((size_t)N_ * DIM_H * 4);
    float* xl      = (float*)alloc((size_t)N_ * 256 * 4);
    float* xr      = (float*)alloc((size_t)N_ * 256 * 4);
    float* ea_mean = (float*)alloc((size_t)N_ * DIM_ED * 4);
    int*   deg     = (int*)alloc((size_t)N_ * 4);
    int*   off     = (int*)alloc((size_t)(N_ + 1) * 4);
    int*   cursor  = (int*)alloc((size_t)N_ * 4);
    int*   eid     = (int*)alloc((size_t)(E_ + N_) * 4);
    int*   csrc    = (int*)alloc((size_t)(E_ + N_) * 4);

    hipMemsetAsync(deg, 0, (size_t)N_ * 4, stream);
    hipMemsetAsync(cursor, 0, (size_t)N_ * 4, stream);

    deg_kernel<<<(E_ + 255) / 256, 256, 0, stream>>>(tgt, deg, E_);
    scan_kernel<<<1, 1024, 0, stream>>>(deg, off, N_);
    scatter_kernel<<<(E_ + N_ + 255) / 256, 256, 0, stream>>>(tgt, src, off, cursor, eid, csrc, E_, N_);
    ea_mean_kernel<<<(N_ * DIM_ED + 255) / 256, 256, 0, stream>>>(edge_attr, eid, off, ea_mean, N_, E_);

    in_proj_kernel<<<N_ / 8, 128, 0, stream>>>(x, W0, b0, h0);

    float* hc = h0;
    float* hn = h1;
    for (int l = 0; l < 3; l++) {
        node_proj_kernel<<<N_ / 8, 256, 0, stream>>>(
            hc, Wl + (size_t)l * DIM_H * 256, bl + (size_t)l * 256,
            Wr + (size_t)l * DIM_H * 256, br + (size_t)l * 256, xl, xr);
        gat_attn_kernel<<<N_ / 4, 256, 0, stream>>>(
            xl, xr, edge_attr, ea_mean, csrc, eid, off,
            We + (size_t)l * DIM_ED * 256, att + (size_t)l * 256, bconv + (size_t)l * DIM_H,
            hn, N_, E_);
        float* tswap = hc; hc = hn; hn = tswap;
    }
    decoder_kernel<<<N_ / 4, 128, 0, stream>>>(hc, W1, b1, W2, b2, out);
}